// Round 4
// baseline (95.336 us; speedup 1.0000x reference)
//
#include <hip/hip_runtime.h>
#include <cmath>

#define BB 64
#define KK 100
#define QQ 100
#define CC 82
#define AA 118
#define KP1 101
#define AM1 117
#define ROWF (KK * KP1)        // 10100 floats per (b,a) row (multiple of 4)
#define SROWS 13               // a-rows per block; 117 = 13*9
#define NCHUNK 9
#define CHUNKF (SROWS * ROWF)  // 131300 floats per block
#define CHUNK4 (CHUNKF / 4)    // 32825 float4 per block
#define TW 2528                // uint words for 10100-byte table (2525 rounded)

// One kernel does everything. grid = BB*NCHUNK blocks of 512.
// Each block: (redundant per-batch prep in LDS) then streams a contiguous
// 13-row chunk of pair_score with inline values (no atomics, no 2nd pass).
__global__ __launch_bounds__(512) void fused_kernel(
    const float* __restrict__ logits,   // B,K,C
    const float* __restrict__ boxes_in, // B,K,4
    const float* __restrict__ actions,  // B,Q,A
    const float* __restrict__ hidx,     // B,Q,K
    const float* __restrict__ oidx,     // B,Q,K
    const int*   __restrict__ tsizes,   // B,2
    float* __restrict__ out_scores,     // B,K
    float* __restrict__ out_labels,     // B,K
    float* __restrict__ out_boxes,      // B,K,4
    float* __restrict__ out_pair)       // B,117,100,101
{
    int blk = blockIdx.x;
    int b = blk / NCHUNK;
    int chunk = blk - b * NCHUNK;
    int tid = threadIdx.x;

    __shared__ unsigned T32[TW];        // byte table: f -> sorted pos+1 (0 = none)
    __shared__ int   sh_h[QQ], sh_o[QQ];
    __shared__ float sh_ms[QQ], sh_labf[KK], sh_score[KK];
    __shared__ int   sh_spos[KK];
    __shared__ float sh_coef[QQ];
    __shared__ int   sh_f[QQ];
    __shared__ int   sf[QQ + 1];        // f-sorted segment ids, -1 sentinel
    __shared__ float sc[QQ];            // coef, sorted
    __shared__ int   sq[QQ];            // query id, sorted

    // ---- phase A: zero table + per-k / per-q parallel tasks ----
    for (int i = tid; i < TW; i += 512) T32[i] = 0u;
    if (tid <= QQ) sf[tid] = -1;

    if (tid < QQ) {
        // q = tid: argmax over hidx row (first-occurrence ties via strict >)
        const float4* rp = (const float4*)(hidx + ((size_t)b * QQ + tid) * KK);
        float best = -INFINITY; int bi = 0;
        #pragma unroll
        for (int i = 0; i < KK / 4; ++i) {
            float4 r = rp[i];
            if (r.x > best) { best = r.x; bi = 4 * i; }
            if (r.y > best) { best = r.y; bi = 4 * i + 1; }
            if (r.z > best) { best = r.z; bi = 4 * i + 2; }
            if (r.w > best) { best = r.w; bi = 4 * i + 3; }
        }
        sh_h[tid] = bi;
    } else if (tid < 2 * QQ) {
        int q = tid - QQ;
        const float4* rp = (const float4*)(oidx + ((size_t)b * QQ + q) * KK);
        float best = -INFINITY; int bi = 0;
        #pragma unroll
        for (int i = 0; i < KK / 4; ++i) {
            float4 r = rp[i];
            if (r.x > best) { best = r.x; bi = 4 * i; }
            if (r.y > best) { best = r.y; bi = 4 * i + 1; }
            if (r.z > best) { best = r.z; bi = 4 * i + 2; }
            if (r.w > best) { best = r.w; bi = 4 * i + 3; }
        }
        sh_o[q] = bi;
    } else if (tid < 2 * QQ + KK) {
        // softmax-lite for k: label, score, positivity (2-pass streaming, no array)
        int k = tid - 2 * QQ;
        const float2* l2 = (const float2*)(logits + ((size_t)b * KK + k) * CC);
        float m = -INFINITY, best = -INFINITY; int bi = 0;
        #pragma unroll
        for (int i = 0; i < CC / 2; ++i) {
            float2 p = l2[i];
            m = fmaxf(m, fmaxf(p.x, p.y));
            if (p.x > best) { best = p.x; bi = 2 * i; }
            if (2 * i + 1 < CC - 1 && p.y > best) { best = p.y; bi = 2 * i + 1; }
        }
        // note: element CC-1 (=81, the "no-object" class) excluded from best
        float denom = 0.f;
        #pragma unroll
        for (int i = 0; i < CC / 2; ++i) {
            float2 p = l2[i];
            denom += expf(p.x - m) + expf(p.y - m);
        }
        float score = expf(best - m) / denom;
        sh_labf[k]  = (float)bi;
        sh_score[k] = score;
        sh_spos[k]  = (score > 0.0f) ? 1 : 0;
        if (chunk == 0) {
            out_scores[b * KK + k] = score;
            out_labels[b * KK + k] = (float)bi;
        }
    } else if (tid < 3 * QQ + KK) {
        int q = tid - (2 * QQ + KK);
        float x = actions[((size_t)b * QQ + q) * AA + (AA - 1)];
        sh_ms[q] = 1.f - 1.f / (1.f + expf(-x));
    } else if (chunk == 0 && tid >= 400 && tid < 400 + KK) {
        int k = tid - 400;
        const float4 bx = *(const float4*)(boxes_in + ((size_t)b * KK + k) * 4);
        float ihh = (float)tsizes[b * 2 + 0];
        float iww = (float)tsizes[b * 2 + 1];
        float4 ob;
        ob.x = (bx.x - 0.5f * bx.z) * iww;
        ob.y = (bx.y - 0.5f * bx.w) * ihh;
        ob.z = (bx.x + 0.5f * bx.z) * iww;
        ob.w = (bx.y + 0.5f * bx.w) * ihh;
        *(float4*)(out_boxes + ((size_t)b * KK + k) * 4) = ob;
    }
    __syncthreads();

    // ---- phase B: winner per segment + masked coefficient ----
    if (tid < QQ) {
        int hh = sh_h[tid], oo = sh_o[tid];
        int f = hh * KP1 + oo;
        float myms = sh_ms[tid];
        bool winf = true;
        for (int q = 0; q < QQ; ++q) {
            if (sh_h[q] * KP1 + sh_o[q] == f) {
                float m2 = sh_ms[q];
                if (m2 > myms || (m2 == myms && q < tid)) { winf = false; break; }
            }
        }
        float hm = (sh_labf[hh] == 1.0f && sh_spos[hh]) ? 1.f : 0.f;
        float om = sh_spos[oo] ? 1.f : 0.f;
        sh_f[tid]    = f;
        sh_coef[tid] = myms * (winf ? 2.f : 1.f) * hm * om;
    }
    __syncthreads();

    // ---- phase C: compact+sort nonzero entries by (f, q); build byte table ----
    if (tid < QQ) {
        float c = sh_coef[tid];
        if (c != 0.f) {
            int ft = sh_f[tid];
            int pos = 0, eqbefore = 0;
            for (int j = 0; j < QQ; ++j) {
                if (sh_coef[j] != 0.f) {
                    int fj = sh_f[j];
                    if (fj < ft || (fj == ft && j < tid)) ++pos;
                    if (fj == ft && j < tid) ++eqbefore;
                }
            }
            sf[pos] = ft;
            sc[pos] = c;
            sq[pos] = tid;
            if (eqbefore == 0) ((unsigned char*)T32)[ft] = (unsigned char)(pos + 1);
        }
    }
    __syncthreads();

    // ---- stream: one contiguous 525KB chunk, inline values ----
    const float* actb = actions + (size_t)b * QQ * AA;
    float* base = out_pair + ((size_t)(b * AM1 + chunk * SROWS)) * ROWF;
    int e = tid * 4;
    int a_off = e / ROWF;                  // 0..12 (e < 2048*4 < 10100 -> 0, but keep general)
    int f = e - a_off * ROWF;
    int a = chunk * SROWS + a_off;
    for (int p = tid; p < CHUNK4; p += 512) {
        unsigned w = T32[f >> 2];          // 4 table bytes for f..f+3 (f % 4 == 0)
        float4 v = make_float4(0.f, 0.f, 0.f, 0.f);
        if (w) {
            float* vp = &v.x;
            #pragma unroll
            for (int j = 0; j < 4; ++j) {
                int byte = (int)((w >> (8 * j)) & 0xFFu);
                if (byte) {
                    int pp = byte - 1;
                    int fj = f + j;
                    float s = 0.f;
                    while (sf[pp] == fj) {
                        float x = actb[sq[pp] * AA + a];
                        s += sc[pp] / (1.f + expf(-x));
                        ++pp;
                    }
                    vp[j] = s;
                }
            }
        }
        *(float4*)(base + e) = v;
        e += 2048;
        f += 2048;
        if (f >= ROWF) { f -= ROWF; ++a; }
    }
}

extern "C" void kernel_launch(void* const* d_in, const int* in_sizes, int n_in,
                              void* d_out, int out_size, void* d_ws, size_t ws_size,
                              hipStream_t stream) {
    const float* pred_logits  = (const float*)d_in[0];
    const float* pred_boxes   = (const float*)d_in[1];
    const float* pred_actions = (const float*)d_in[2];
    const float* pred_hidx    = (const float*)d_in[3];
    const float* pred_oidx    = (const float*)d_in[4];
    const int*   target_sizes = (const int*)d_in[5];

    float* out = (float*)d_out;
    float* out_scores = out;                // B*K
    float* out_labels = out + BB * KK;      // B*K
    float* out_boxes  = out + 2 * BB * KK;  // B*K*4
    float* out_pair   = out + 6 * BB * KK;  // B*117*100*101

    fused_kernel<<<BB * NCHUNK, 512, 0, stream>>>(
        pred_logits, pred_boxes, pred_actions, pred_hidx, pred_oidx,
        target_sizes, out_scores, out_labels, out_boxes, out_pair);
}